// Round 7
// baseline (176.477 us; speedup 1.0000x reference)
//
#include <hip/hip_runtime.h>
#include <hip/hip_bf16.h>

// MixtureExperts as dense GEMM: out[2048,16384] = G[2048,64] @ W[64,16384]
//   G[b,e] = count_k(idx[b,k]==e) * sel[b,e]   (exact duplicate handling)
// K=64 -> 2x mfma_f32_16x16x32_bf16 per 16x16 output tile.
// Roofline: 128 MiB fp32 output writes ~= 21 us @ 6.3 TB/s.
//
// Fragment layouts (guide §3, m89-verified):
//   A lane l: A[m=l&15][k=8*(l>>4)+j]   -> needs [m][k] storage (row-contig k)
//   B lane l: B[k=8*(l>>4)+j][n=l&15]   -> needs [n][k] storage (row-contig k)
//   D lane l reg r: D[row=4*(l>>4)+r][col=l&15]
// We put Wt[n][e] on the A side (m-dim = n) and G[b][e] on the B side
// (n-dim = b): both operands are natural [row][k=e] arrays, and D rows
// (4*kg+r) are 4 CONSECUTIVE n -> one f32x4 non-temporal store per tile.

constexpr int BS = 2048, NE = 64, TK = 8;
constexpr int PD = 32 * 512;   // 16384

typedef float          f32x4 __attribute__((ext_vector_type(4)));
typedef short          s16x8 __attribute__((ext_vector_type(8)));
typedef unsigned short u16x4 __attribute__((ext_vector_type(4)));
typedef unsigned short u16x8 __attribute__((ext_vector_type(8)));

__device__ __forceinline__ unsigned short f2bf(float f) {
    __hip_bfloat16 h = __float2bfloat16(f);   // library RNE
    return __builtin_bit_cast(unsigned short, h);
}

// --- kernel 1: dense gate G[b][e] (bf16). One wave per row, lane = expert. ---
__global__ __launch_bounds__(256) void build_gate(
    const float* __restrict__ sel, const int* __restrict__ idx,
    unsigned short* __restrict__ G)
{
    const int b = blockIdx.x * 4 + (threadIdx.x >> 6);
    const int e = threadIdx.x & 63;
    int cnt = 0;
#pragma unroll
    for (int k = 0; k < TK; ++k) cnt += (idx[b * TK + k] == e) ? 1 : 0;
    G[b * NE + e] = f2bf((float)cnt * sel[b * NE + e]);
}

// --- kernel 2: Wt[n][e] = bf16(W[e][n]) via LDS transpose, 128-col tiles ---
__global__ __launch_bounds__(256) void build_wt(
    const float* __restrict__ W, unsigned short* __restrict__ Wt)
{
    __shared__ unsigned short lds[NE][128];   // 16 KiB
    const int n0 = blockIdx.x * 128;
    const int t  = threadIdx.x;

    for (int i = t; i < NE * 32; i += 256) {          // 64 experts x 32 f32x4
        const int e = i >> 5, n4 = i & 31;
        const f32x4 w = *reinterpret_cast<const f32x4*>(W + (size_t)e * PD + n0 + n4 * 4);
        u16x4 r;
#pragma unroll
        for (int j = 0; j < 4; ++j) r[j] = f2bf(w[j]);
        *reinterpret_cast<u16x4*>(&lds[e][n4 * 4]) = r;
    }
    __syncthreads();

    if (t < 128) {                                     // thread t -> row n0+t
        unsigned short* dst = Wt + (size_t)(n0 + t) * NE;
#pragma unroll
        for (int j = 0; j < 8; ++j) {
            u16x8 v;
#pragma unroll
            for (int jj = 0; jj < 8; ++jj) v[jj] = lds[j * 8 + jj][t];
            *reinterpret_cast<u16x8*>(dst + j * 8) = v;
        }
    }
}

// --- kernel 3: GEMM, no LDS; fragments straight from L1/L2 ---
__global__ __launch_bounds__(256) void gemm_moe(
    const unsigned short* __restrict__ G,    // [BS][NE] bf16
    const unsigned short* __restrict__ Wt,   // [PD][NE] bf16
    float* __restrict__ out)                 // [BS][PD]
{
    const int t   = threadIdx.x;
    const int w   = t >> 6, l = t & 63;
    const int col = l & 15, kg = l >> 4;

    const int bt  = blockIdx.x & 31;          // 32 batch-tiles of 64 rows
    const int nb  = blockIdx.x >> 5;          // 128 n-tiles of 128 cols
    const int mb  = bt * 64 + w * 16;         // this wave's 16 batch rows
    const int nt0 = nb * 128;

    const short* Gs  = reinterpret_cast<const short*>(G);
    const short* Wts = reinterpret_cast<const short*>(Wt);

    // B-operand fragments (gate rows), loaded once, reused over 8 n-subtiles
    const s16x8 gb0 = *reinterpret_cast<const s16x8*>(Gs + (mb + col) * NE + 8 * kg);
    const s16x8 gb1 = *reinterpret_cast<const s16x8*>(Gs + (mb + col) * NE + 32 + 8 * kg);

#pragma unroll
    for (int s = 0; s < 8; ++s) {
        const int n0 = nt0 + s * 16;
        const s16x8 a0 = *reinterpret_cast<const s16x8*>(
            Wts + (size_t)(n0 + col) * NE + 8 * kg);
        const s16x8 a1 = *reinterpret_cast<const s16x8*>(
            Wts + (size_t)(n0 + col) * NE + 32 + 8 * kg);
        f32x4 c = {0.f, 0.f, 0.f, 0.f};
        c = __builtin_amdgcn_mfma_f32_16x16x32_bf16(a0, gb0, c, 0, 0, 0);
        c = __builtin_amdgcn_mfma_f32_16x16x32_bf16(a1, gb1, c, 0, 0, 0);
        // D: rows 4*kg..4*kg+3 are consecutive n; col is the batch row.
        __builtin_nontemporal_store(c, reinterpret_cast<f32x4*>(
            out + (size_t)(mb + col) * PD + n0 + 4 * kg));
    }
}

// --- fallback if ws too small: round-2 fp32 gather ---
__global__ __launch_bounds__(256) void moe_mix_f32(
    const float* __restrict__ sel, const int* __restrict__ idx,
    const float* __restrict__ W, float* __restrict__ out)
{
    const int b = blockIdx.x, t = threadIdx.x;
    int e[TK]; float s[TK];
#pragma unroll
    for (int k = 0; k < TK; ++k) {
        e[k] = idx[b * TK + k];
        s[k] = sel[b * NE + e[k]];
    }
    const f32x4* W4 = reinterpret_cast<const f32x4*>(W);
    f32x4*       O4 = reinterpret_cast<f32x4*>(out) + (size_t)b * (PD / 4);
#pragma unroll 2
    for (int j = 0; j < (PD / 4) / 256; ++j) {
        const int f4 = t + j * 256;
        f32x4 acc = (f32x4)(0.f);
#pragma unroll
        for (int k = 0; k < TK; ++k)
            acc += s[k] * W4[(size_t)e[k] * (PD / 4) + f4];
        __builtin_nontemporal_store(acc, &O4[f4]);
    }
}

extern "C" void kernel_launch(void* const* d_in, const int* in_sizes, int n_in,
                              void* d_out, int out_size, void* d_ws, size_t ws_size,
                              hipStream_t stream) {
    const float* sel = (const float*)d_in[0];
    const int*   idx = (const int*)d_in[1];
    const float* W   = (const float*)d_in[2];
    float*       out = (float*)d_out;

    const size_t needG  = (size_t)BS * NE * sizeof(unsigned short);  // 256 KiB
    const size_t needWt = (size_t)PD * NE * sizeof(unsigned short);  // 2 MiB

    if (ws_size >= needG + needWt) {
        unsigned short* G  = (unsigned short*)d_ws;
        unsigned short* Wt = (unsigned short*)d_ws + (size_t)BS * NE;
        build_gate<<<dim3(BS / 4), dim3(256), 0, stream>>>(sel, idx, G);
        build_wt  <<<dim3(PD / 128), dim3(256), 0, stream>>>(W, Wt);
        gemm_moe  <<<dim3(32 * 128), dim3(256), 0, stream>>>(G, Wt, out);
    } else {
        moe_mix_f32<<<dim3(BS), dim3(256), 0, stream>>>(sel, idx, W, out);
    }
}